// Round 2
// baseline (751.091 us; speedup 1.0000x reference)
//
#include <hip/hip_runtime.h>

// ---------------------------------------------------------------------------
// RGCN-ish stack on MI355X, f32 (no fp32 MFMA on CDNA4 -> vector-ALU GEMMs).
//
// Plan per call:
//   1. Build CSR-by-dst once (degree -> scan -> scatter, packed src|et<<17).
//   2. x = h @ W_fc                       (tiled f32 GEMM, K=128)
//   3. 3x layers:
//        pre[dst][r][:] = sum of x[src] over in-edges of relation r (CSR, wave/dst)
//        x = relu([pre | x] @ [W_rels[l] ; W_loops[l]] + b[l])   (K=320 GEMM)
//   4. out = sum_n sum_f x[n][f] * W_dense[f] + b_dense
//
// Rationale: aggregating RAW x (25.6 MB gather footprint, L2/LLC-resident)
// instead of per-relation transformed features (102 MB) keeps the gather
// cache-friendly; the 4 relation partial sums recombine in ONE fused GEMM
// of K=256+64, which also absorbs self-loop + bias + ReLU.
// ---------------------------------------------------------------------------

// ------------------------- preprocessing -----------------------------------

__global__ void k_degree(const int* __restrict__ dst, int* __restrict__ deg, int E) {
  int i = blockIdx.x * blockDim.x + threadIdx.x;
  if (i < E) atomicAdd(&deg[dst[i]], 1);
}

__global__ __launch_bounds__(1024) void k_scan1(const int* __restrict__ deg,
                                                int* __restrict__ scan,
                                                int* __restrict__ part, int N) {
  __shared__ int s[1024];
  int tid = threadIdx.x;
  int idx = blockIdx.x * 1024 + tid;
  int v = (idx < N) ? deg[idx] : 0;
  s[tid] = v;
  __syncthreads();
  for (int off = 1; off < 1024; off <<= 1) {
    int t = (tid >= off) ? s[tid - off] : 0;
    __syncthreads();
    s[tid] += t;
    __syncthreads();
  }
  if (idx < N) scan[idx] = s[tid];
  if (tid == 1023) part[blockIdx.x] = s[1023];
}

// nblk = ceil(N/1024) = 98 for N=100000 -> fits one 1024-thread block.
__global__ __launch_bounds__(1024) void k_scan2(const int* __restrict__ part,
                                                int* __restrict__ partx, int nblk) {
  __shared__ int s[1024];
  int tid = threadIdx.x;
  int v = (tid < nblk) ? part[tid] : 0;
  s[tid] = v;
  __syncthreads();
  for (int off = 1; off < 1024; off <<= 1) {
    int t = (tid >= off) ? s[tid - off] : 0;
    __syncthreads();
    s[tid] += t;
    __syncthreads();
  }
  if (tid < nblk) partx[tid] = s[tid] - v;  // exclusive offset per block
}

__global__ void k_scan3(const int* __restrict__ scan, const int* __restrict__ deg,
                        const int* __restrict__ partx, int* __restrict__ rowptr,
                        int* __restrict__ cursor, int N, int E) {
  int i = blockIdx.x * blockDim.x + threadIdx.x;
  if (i < N) {
    int v = scan[i] - deg[i] + partx[i >> 10];  // exclusive scan
    rowptr[i] = v;
    cursor[i] = v;
  }
  if (i == 0) rowptr[N] = E;
}

__global__ void k_scatter(const int* __restrict__ src, const int* __restrict__ dst,
                          const int* __restrict__ et, int* __restrict__ cursor,
                          unsigned* __restrict__ edata, int E) {
  int i = blockIdx.x * blockDim.x + threadIdx.x;
  if (i < E) {
    int d = dst[i];
    int pos = atomicAdd(&cursor[d], 1);
    // src < 2^17 (N=100000 structural), etype < 4 -> pack into one u32
    edata[pos] = (unsigned)src[i] | ((unsigned)et[i] << 17);
  }
}

// ------------------------- per-layer aggregation ----------------------------
// One wave per dst node; lane = feature (H=64). 4 relation accumulators in
// registers (static names — runtime-indexed arrays would go to scratch);
// CSR order -> deterministic, no atomics, no pre-zeroing needed.

__global__ __launch_bounds__(256) void k_agg(const int* __restrict__ rowptr,
                                             const unsigned* __restrict__ edata,
                                             const float* __restrict__ x,
                                             float* __restrict__ pre, int N) {
  int wid = (blockIdx.x * blockDim.x + threadIdx.x) >> 6;
  int lane = threadIdx.x & 63;
  if (wid >= N) return;
  int beg = rowptr[wid];
  int end = rowptr[wid + 1];
  float a0 = 0.f, a1 = 0.f, a2 = 0.f, a3 = 0.f;
  int e = beg;
  for (; e + 4 <= end; e += 4) {
    // edata[e] is wave-uniform: readfirstlane -> scalar addr math + saddr loads
    unsigned p0 = __builtin_amdgcn_readfirstlane(edata[e]);
    unsigned p1 = __builtin_amdgcn_readfirstlane(edata[e + 1]);
    unsigned p2 = __builtin_amdgcn_readfirstlane(edata[e + 2]);
    unsigned p3 = __builtin_amdgcn_readfirstlane(edata[e + 3]);
    float v0 = x[(size_t)(p0 & 0x1FFFF) * 64 + lane];
    float v1 = x[(size_t)(p1 & 0x1FFFF) * 64 + lane];
    float v2 = x[(size_t)(p2 & 0x1FFFF) * 64 + lane];
    float v3 = x[(size_t)(p3 & 0x1FFFF) * 64 + lane];
    { int t = p0 >> 17; if (t == 0) a0 += v0; else if (t == 1) a1 += v0; else if (t == 2) a2 += v0; else a3 += v0; }
    { int t = p1 >> 17; if (t == 0) a0 += v1; else if (t == 1) a1 += v1; else if (t == 2) a2 += v1; else a3 += v1; }
    { int t = p2 >> 17; if (t == 0) a0 += v2; else if (t == 1) a1 += v2; else if (t == 2) a2 += v2; else a3 += v2; }
    { int t = p3 >> 17; if (t == 0) a0 += v3; else if (t == 1) a1 += v3; else if (t == 2) a2 += v3; else a3 += v3; }
  }
  for (; e < end; ++e) {
    unsigned p = __builtin_amdgcn_readfirstlane(edata[e]);
    float v = x[(size_t)(p & 0x1FFFF) * 64 + lane];
    int t = p >> 17;
    if (t == 0) a0 += v; else if (t == 1) a1 += v; else if (t == 2) a2 += v; else a3 += v;
  }
  float* o = pre + (size_t)wid * 256 + lane;
  o[0] = a0; o[64] = a1; o[128] = a2; o[192] = a3;
}

// ------------------------- tiled f32 GEMM -----------------------------------
// C[M x 64] = act( [A0 | A1] @ [B0 ; B1] + bias ),  K0/K1 multiples of 32.
// Block: 256 threads, 128x64 output tile, 8x4 per thread, K-chunk 32.
// LDS bank check: As reads broadcast within ty-group (free); Bs reads are
// 2-way (free per m136); As transpose-stores are 2-way (free).

__global__ __launch_bounds__(256) void k_gemm(
    const float* __restrict__ A0, int K0,
    const float* __restrict__ A1, int K1,
    const float* __restrict__ B0, const float* __restrict__ B1,
    const float* __restrict__ bias, int relu,
    float* __restrict__ C, int M) {
  __shared__ float As[32][132];  // [k][row], row-stride 132 floats
  __shared__ float Bs[32][64];   // [k][col]
  const int tid = threadIdx.x;
  const int tx = tid & 15;   // col group: 16 x 4 = 64 cols
  const int ty = tid >> 4;   // row group: 16 x 8 = 128 rows
  const int row0 = blockIdx.x * 128;

  float acc[8][4];
#pragma unroll
  for (int i = 0; i < 8; ++i)
#pragma unroll
    for (int j = 0; j < 4; ++j) acc[i][j] = 0.f;

  const int K = K0 + K1;
  for (int kb = 0; kb < K; kb += 32) {
    const float* Ap; int lda, kloc;
    const float* Bp;
    if (kb < K0) { Ap = A0; lda = K0; kloc = kb;      Bp = B0 + kb * 64; }
    else         { Ap = A1; lda = K1; kloc = kb - K0; Bp = B1 + (kb - K0) * 64; }

    // stage A chunk transposed: thread covers one row-half (16 consecutive k)
    {
      const int r = tid >> 1;
      const int kk0 = (tid & 1) * 16;
      const int grow = row0 + r;
      float vv[16];
      if (grow < M) {
        const float* s = Ap + (size_t)grow * lda + kloc + kk0;
#pragma unroll
        for (int q = 0; q < 4; ++q)
          *reinterpret_cast<float4*>(&vv[q * 4]) =
              *reinterpret_cast<const float4*>(s + q * 4);
      } else {
#pragma unroll
        for (int q = 0; q < 16; ++q) vv[q] = 0.f;
      }
#pragma unroll
      for (int q = 0; q < 16; ++q) As[kk0 + q][r] = vv[q];
    }
    // stage B chunk (already [k][col])
    {
      const int kr = tid >> 3;
      const int f0 = (tid & 7) * 8;
      const float* s = Bp + kr * 64 + f0;
      *reinterpret_cast<float4*>(&Bs[kr][f0]) = *reinterpret_cast<const float4*>(s);
      *reinterpret_cast<float4*>(&Bs[kr][f0 + 4]) = *reinterpret_cast<const float4*>(s + 4);
    }
    __syncthreads();

#pragma unroll
    for (int kk = 0; kk < 32; ++kk) {
      float a[8], b[4];
      *reinterpret_cast<float4*>(&a[0]) = *reinterpret_cast<const float4*>(&As[kk][ty * 8]);
      *reinterpret_cast<float4*>(&a[4]) = *reinterpret_cast<const float4*>(&As[kk][ty * 8 + 4]);
      *reinterpret_cast<float4*>(&b[0]) = *reinterpret_cast<const float4*>(&Bs[kk][tx * 4]);
#pragma unroll
      for (int i = 0; i < 8; ++i)
#pragma unroll
        for (int j = 0; j < 4; ++j) acc[i][j] += a[i] * b[j];
    }
    __syncthreads();
  }

  float bc[4];
#pragma unroll
  for (int j = 0; j < 4; ++j) bc[j] = bias ? bias[tx * 4 + j] : 0.f;
#pragma unroll
  for (int i = 0; i < 8; ++i) {
    const int r = row0 + ty * 8 + i;
    if (r < M) {
      float o[4];
#pragma unroll
      for (int j = 0; j < 4; ++j) {
        float v = acc[i][j] + bc[j];
        o[j] = relu ? fmaxf(v, 0.f) : v;
      }
      *reinterpret_cast<float4*>(C + (size_t)r * 64 + tx * 4) =
          *reinterpret_cast<const float4*>(o);
    }
  }
}

// ------------------------- final pooling ------------------------------------

__global__ __launch_bounds__(256) void k_pool(const float* __restrict__ x,
                                              const float* __restrict__ Wd,
                                              float* __restrict__ accum, int total) {
  __shared__ float red[256];
  int tid = threadIdx.x;
  float s = 0.f;
  for (int i = blockIdx.x * 256 + tid; i < total; i += gridDim.x * 256)
    s += x[i] * Wd[i & 63];
  red[tid] = s;
  __syncthreads();
  for (int off = 128; off > 0; off >>= 1) {
    if (tid < off) red[tid] += red[tid + off];
    __syncthreads();
  }
  if (tid == 0) atomicAdd(accum, red[0]);
}

__global__ void k_final(const float* __restrict__ accum, const float* __restrict__ b,
                        float* __restrict__ out) {
  out[0] = accum[0] + b[0];
}

// ------------------------- launch -------------------------------------------

extern "C" void kernel_launch(void* const* d_in, const int* in_sizes, int n_in,
                              void* d_out, int out_size, void* d_ws, size_t ws_size,
                              hipStream_t stream) {
  const float* h       = (const float*)d_in[0];
  const int*   src     = (const int*)d_in[1];
  const int*   dst     = (const int*)d_in[2];
  const int*   et      = (const int*)d_in[3];
  const float* W_fc    = (const float*)d_in[4];
  const float* W_rels  = (const float*)d_in[5];
  const float* W_loops = (const float*)d_in[6];
  const float* biases  = (const float*)d_in[7];
  const float* W_dense = (const float*)d_in[8];
  const float* b_dense = (const float*)d_in[9];
  float* out = (float*)d_out;

  const int N = in_sizes[0] / 128;
  const int E = in_sizes[1];

  // workspace carve-up (~162 MB total)
  size_t cur = 0;
  auto carve = [&](size_t bytes) -> char* {
    cur = (cur + 255) & ~(size_t)255;
    char* p = (char*)d_ws + cur;
    cur += bytes;
    return p;
  };
  int* deg        = (int*)carve((size_t)N * 4);
  int* scan       = (int*)carve((size_t)N * 4);
  int* part       = (int*)carve(1024 * 4);
  int* partx      = (int*)carve(1024 * 4);
  int* rowptr     = (int*)carve((size_t)(N + 1) * 4);
  int* cursor     = (int*)carve((size_t)N * 4);
  unsigned* edata = (unsigned*)carve((size_t)E * 4);
  float* xA       = (float*)carve((size_t)N * 64 * 4);
  float* xB       = (float*)carve((size_t)N * 64 * 4);
  float* pre      = (float*)carve((size_t)N * 256 * 4);
  float* accum    = (float*)carve(256);

  hipMemsetAsync(deg, 0, (size_t)N * 4, stream);
  hipMemsetAsync(accum, 0, 4, stream);

  const int eb = (E + 255) / 256;
  k_degree<<<eb, 256, 0, stream>>>(dst, deg, E);
  const int nblk = (N + 1023) / 1024;
  k_scan1<<<nblk, 1024, 0, stream>>>(deg, scan, part, N);
  k_scan2<<<1, 1024, 0, stream>>>(part, partx, nblk);
  k_scan3<<<(N + 255) / 256, 256, 0, stream>>>(scan, deg, partx, rowptr, cursor, N, E);
  k_scatter<<<eb, 256, 0, stream>>>(src, dst, et, cursor, edata, E);

  const int gb = (N + 127) / 128;
  // x = h @ W_fc   (no bias, no relu)
  k_gemm<<<gb, 256, 0, stream>>>(h, 128, nullptr, 0, W_fc, nullptr, nullptr, 0, xA, N);

  float* xin = xA;
  float* xout = xB;
  for (int l = 0; l < 3; ++l) {
    k_agg<<<(N + 3) / 4, 256, 0, stream>>>(rowptr, edata, xin, pre, N);
    k_gemm<<<gb, 256, 0, stream>>>(pre, 256, xin, 64,
                                   W_rels + (size_t)l * 4 * 64 * 64,
                                   W_loops + (size_t)l * 64 * 64,
                                   biases + (size_t)l * 64, 1, xout, N);
    float* t = xin; xin = xout; xout = t;
  }

  k_pool<<<1024, 256, 0, stream>>>(xin, W_dense, accum, N * 64);
  k_final<<<1, 1, 0, stream>>>(accum, b_dense, out);
}

// Round 5
// 667.566 us; speedup vs baseline: 1.1251x; 1.1251x over previous
//
#include <hip/hip_runtime.h>

// ---------------------------------------------------------------------------
// RGCN-ish stack on MI355X.
//   1. CSR-by-dst build (degree -> scan -> scatter, packed src|et<<17).
//   2. B matrices pre-split into bf16 hi/mid/lo fragment-ordered buffers.
//   3. x = h @ W_fc                        (bf16x3 MFMA GEMM, K=128)
//   4. 3x layers:
//        pre[dst][r][:] = sum of x[src] over in-edges of rel r   (k_agg, f32)
//        x = relu([pre | x] @ [W_rels[l] ; W_loops[l]] + b[l])   (MFMA, K=320)
//      last layer: epilogue computes sum_n y[n][f]*W_dense[f] directly.
//   5. out = accum + b_dense
//
// bf16x3 split (a = hi+mid+lo, 6 MFMA products) keeps error ~2^-24 (f32-level)
// while moving all GEMM FLOPs to the matrix cores -> GEMMs become HBM-bound.
// ---------------------------------------------------------------------------

typedef __attribute__((ext_vector_type(8))) short short8;
typedef __attribute__((ext_vector_type(4))) float f32x4;

__device__ inline unsigned short f32_to_bf16_rne(float x) {
  unsigned u = __builtin_bit_cast(unsigned, x);
  unsigned r = (u + 0x7FFFu + ((u >> 16) & 1u)) >> 16;
  return (unsigned short)r;
}
__device__ inline float bf16_bits_to_f32(unsigned short b) {
  unsigned u = ((unsigned)b) << 16;
  return __builtin_bit_cast(float, u);
}

// ------------------------- preprocessing -----------------------------------

__global__ void k_degree(const int* __restrict__ dst, int* __restrict__ deg, int E) {
  int i = blockIdx.x * blockDim.x + threadIdx.x;
  if (i < E) atomicAdd(&deg[dst[i]], 1);
}

__global__ __launch_bounds__(1024) void k_scan1(const int* __restrict__ deg,
                                                int* __restrict__ scan,
                                                int* __restrict__ part, int N) {
  __shared__ int s[1024];
  int tid = threadIdx.x;
  int idx = blockIdx.x * 1024 + tid;
  int v = (idx < N) ? deg[idx] : 0;
  s[tid] = v;
  __syncthreads();
  for (int off = 1; off < 1024; off <<= 1) {
    int t = (tid >= off) ? s[tid - off] : 0;
    __syncthreads();
    s[tid] += t;
    __syncthreads();
  }
  if (idx < N) scan[idx] = s[tid];
  if (tid == 1023) part[blockIdx.x] = s[1023];
}

__global__ __launch_bounds__(1024) void k_scan2(const int* __restrict__ part,
                                                int* __restrict__ partx, int nblk) {
  __shared__ int s[1024];
  int tid = threadIdx.x;
  int v = (tid < nblk) ? part[tid] : 0;
  s[tid] = v;
  __syncthreads();
  for (int off = 1; off < 1024; off <<= 1) {
    int t = (tid >= off) ? s[tid - off] : 0;
    __syncthreads();
    s[tid] += t;
    __syncthreads();
  }
  if (tid < nblk) partx[tid] = s[tid] - v;
}

__global__ void k_scan3(const int* __restrict__ scan, const int* __restrict__ deg,
                        const int* __restrict__ partx, int* __restrict__ rowptr,
                        int* __restrict__ cursor, int N, int E) {
  int i = blockIdx.x * blockDim.x + threadIdx.x;
  if (i < N) {
    int v = scan[i] - deg[i] + partx[i >> 10];
    rowptr[i] = v;
    cursor[i] = v;
  }
  if (i == 0) rowptr[N] = E;
}

__global__ void k_scatter(const int* __restrict__ src, const int* __restrict__ dst,
                          const int* __restrict__ et, int* __restrict__ cursor,
                          unsigned* __restrict__ edata, int E) {
  int i = blockIdx.x * blockDim.x + threadIdx.x;
  if (i < E) {
    int d = dst[i];
    int pos = atomicAdd(&cursor[d], 1);
    edata[pos] = (unsigned)src[i] | ((unsigned)et[i] << 17);
  }
}

// ------------------------- per-layer aggregation ----------------------------

__global__ __launch_bounds__(256) void k_agg(const int* __restrict__ rowptr,
                                             const unsigned* __restrict__ edata,
                                             const float* __restrict__ x,
                                             float* __restrict__ pre, int N) {
  int wid = (blockIdx.x * blockDim.x + threadIdx.x) >> 6;
  int lane = threadIdx.x & 63;
  if (wid >= N) return;
  int beg = rowptr[wid];
  int end = rowptr[wid + 1];
  float a0 = 0.f, a1 = 0.f, a2 = 0.f, a3 = 0.f;
  int e = beg;
  for (; e + 4 <= end; e += 4) {
    unsigned p0 = __builtin_amdgcn_readfirstlane(edata[e]);
    unsigned p1 = __builtin_amdgcn_readfirstlane(edata[e + 1]);
    unsigned p2 = __builtin_amdgcn_readfirstlane(edata[e + 2]);
    unsigned p3 = __builtin_amdgcn_readfirstlane(edata[e + 3]);
    float v0 = x[(size_t)(p0 & 0x1FFFF) * 64 + lane];
    float v1 = x[(size_t)(p1 & 0x1FFFF) * 64 + lane];
    float v2 = x[(size_t)(p2 & 0x1FFFF) * 64 + lane];
    float v3 = x[(size_t)(p3 & 0x1FFFF) * 64 + lane];
    { int t = p0 >> 17; if (t == 0) a0 += v0; else if (t == 1) a1 += v0; else if (t == 2) a2 += v0; else a3 += v0; }
    { int t = p1 >> 17; if (t == 0) a0 += v1; else if (t == 1) a1 += v1; else if (t == 2) a2 += v1; else a3 += v1; }
    { int t = p2 >> 17; if (t == 0) a0 += v2; else if (t == 1) a1 += v2; else if (t == 2) a2 += v2; else a3 += v2; }
    { int t = p3 >> 17; if (t == 0) a0 += v3; else if (t == 1) a1 += v3; else if (t == 2) a2 += v3; else a3 += v3; }
  }
  for (; e < end; ++e) {
    unsigned p = __builtin_amdgcn_readfirstlane(edata[e]);
    float v = x[(size_t)(p & 0x1FFFF) * 64 + lane];
    int t = p >> 17;
    if (t == 0) a0 += v; else if (t == 1) a1 += v; else if (t == 2) a2 += v; else a3 += v;
  }
  float* o = pre + (size_t)wid * 256 + lane;
  o[0] = a0; o[64] = a1; o[128] = a2; o[192] = a3;
}

// ------------------------- B pre-split into fragment order ------------------
// Bcat[k][64] (k < K0 from B0, else B1). Frag order for 16x16x32 MFMA:
//   kstep=k>>5, ct=col>>4, lane=(col&15)+16*((k&31)>>3), j=k&7
//   plane[( (kstep*4+ct)*64 + lane )*8 + j]

__global__ void k_bconv(const float* __restrict__ B0, int K0,
                        const float* __restrict__ B1, int K1,
                        unsigned short* __restrict__ Bh,
                        unsigned short* __restrict__ Bm,
                        unsigned short* __restrict__ Bl) {
  int K = K0 + K1;
  int idx = blockIdx.x * 256 + threadIdx.x;
  if (idx >= K * 64) return;
  int k = idx >> 6, col = idx & 63;
  float v;
  if (k < K0)      v = B0[(size_t)k * 64 + col];
  else if (k < K)  v = B1[(size_t)(k - K0) * 64 + col];
  else             v = 0.f;
  int kstep = k >> 5, kk = k & 31;
  int ct = col >> 4;
  int lane = (col & 15) + (((kk >> 3)) << 4);
  int j = kk & 7;
  size_t o = (((size_t)(kstep * 4 + ct)) * 64 + lane) * 8 + j;
  unsigned short hb = f32_to_bf16_rne(v);
  float r1 = v - bf16_bits_to_f32(hb);
  unsigned short mb = f32_to_bf16_rne(r1);
  unsigned short lb = f32_to_bf16_rne(r1 - bf16_bits_to_f32(mb));
  Bh[o] = hb; Bm[o] = mb; Bl[o] = lb;
}

// ------------------------- bf16x3 MFMA GEMM ---------------------------------
// C[M x 64] = act([A0|A1] @ Bcat + bias). Block 256 thr (4 waves), 128-row tile.
// Wave w owns rows w*32..w*32+31 (2 row-tiles of 16), all 64 cols (4 col-tiles).
// A staged f32->hi/mid/lo bf16 in LDS in fragment order; B-frags loaded from
// the pre-split global buffers (L2-resident).
// If pool!=0: skip C write, accumulate sum(relu(y)*Wd[col]) into accum.

__global__ __launch_bounds__(256) void k_mgemm(
    const float* __restrict__ A0, int K0,
    const float* __restrict__ A1, int K1,
    const unsigned short* __restrict__ Bh,
    const unsigned short* __restrict__ Bm,
    const unsigned short* __restrict__ Bl,
    const float* __restrict__ bias, int relu,
    float* __restrict__ C, int M,
    const float* __restrict__ Wd, float* __restrict__ accum, int pool) {
  __shared__ short8 Ah[8 * 64], Am[8 * 64], Al[8 * 64];  // 8 KB each
  __shared__ float red[256];

  const int tid = threadIdx.x;
  const int wave = tid >> 6;
  const int lane = tid & 63;
  const int row0 = blockIdx.x * 128;
  const int K = K0 + K1;

  f32x4 acc[2][4];
#pragma unroll
  for (int i = 0; i < 2; ++i)
#pragma unroll
    for (int j = 0; j < 4; ++j) acc[i][j] = (f32x4){0.f, 0.f, 0.f, 0.f};

  const int srow = tid >> 1;           // staged row 0..127
  const int kk0 = (tid & 1) * 16;      // k-half within 32-chunk
  const int rt_s = srow >> 4;
  const int laneA = (srow & 15) + ((kk0 >> 3) << 4);  // kk0=0 -> +0, kk0=16 -> +32

  for (int kb = 0; kb < K; kb += 32) {
    // ---- stage A chunk: load 16 f32, split to 3 bf16 planes, frag order ----
    {
      const float* Ap;
      int lda;
      if (kb < K0) { Ap = A0 + kb; lda = K0; }
      else         { Ap = A1 + (kb - K0); lda = K1; }
      const int grow = row0 + srow;
      float v[16];
      if (grow < M) {
        const float* s = Ap + (size_t)grow * lda + kk0;
#pragma unroll
        for (int q = 0; q < 4; ++q)
          *reinterpret_cast<float4*>(&v[q * 4]) =
              *reinterpret_cast<const float4*>(s + q * 4);
      } else {
#pragma unroll
        for (int q = 0; q < 16; ++q) v[q] = 0.f;
      }
      short h[16], m[16], l[16];
#pragma unroll
      for (int q = 0; q < 16; ++q) {
        unsigned short hb = f32_to_bf16_rne(v[q]);
        float r1 = v[q] - bf16_bits_to_f32(hb);
        unsigned short mb = f32_to_bf16_rne(r1);
        unsigned short lb = f32_to_bf16_rne(r1 - bf16_bits_to_f32(mb));
        h[q] = (short)hb; m[q] = (short)mb; l[q] = (short)lb;
      }
      short8 H0 = {h[0], h[1], h[2], h[3], h[4], h[5], h[6], h[7]};
      short8 H1 = {h[8], h[9], h[10], h[11], h[12], h[13], h[14], h[15]};
      short8 M0 = {m[0], m[1], m[2], m[3], m[4], m[5], m[6], m[7]};
      short8 M1 = {m[8], m[9], m[10], m[11], m[12], m[13], m[14], m[15]};
      short8 L0 = {l[0], l[1], l[2], l[3], l[4], l[5], l[6], l[7]};
      short8 L1 = {l[8], l[9], l[10], l[11], l[12], l[13], l[14], l[15]};
      Ah[rt_s * 64 + laneA] = H0;
      Ah[rt_s * 64 + laneA + 16] = H1;
      Am[rt_s * 64 + laneA] = M0;
      Am[rt_s * 64 + laneA + 16] = M1;
      Al[rt_s * 64 + laneA] = L0;
      Al[rt_s * 64 + laneA + 16] = L1;
    }
    __syncthreads();

    // ---- fragments + MFMA ----
    const int rt0 = wave * 2, rt1 = rt0 + 1;
    short8 ah0 = Ah[rt0 * 64 + lane], ah1 = Ah[rt1 * 64 + lane];
    short8 am0 = Am[rt0 * 64 + lane], am1 = Am[rt1 * 64 + lane];
    short8 al0 = Al[rt0 * 64 + lane], al1 = Al[rt1 * 64 + lane];
    const int kstep = kb >> 5;
#pragma unroll
    for (int ct = 0; ct < 4; ++ct) {
      size_t bo = (((size_t)(kstep * 4 + ct)) * 64 + lane) * 8;
      short8 bh = *reinterpret_cast<const short8*>(&Bh[bo]);
      short8 bm = *reinterpret_cast<const short8*>(&Bm[bo]);
      short8 bl = *reinterpret_cast<const short8*>(&Bl[bo]);
      acc[0][ct] = __builtin_amdgcn_mfma_f32_16x16x32_bf16(ah0, bh, acc[0][ct], 0, 0, 0);
      acc[0][ct] = __builtin_amdgcn_mfma_f32_16x16x32_bf16(ah0, bm, acc[0][ct], 0, 0, 0);
      acc[0][ct] = __builtin_amdgcn_mfma_f32_16x16x32_bf16(am0, bh, acc[0][ct], 0, 0, 0);
      acc[0][ct] = __builtin_amdgcn_mfma_f32_16x16x32_bf16(ah0, bl, acc[0][ct], 0, 0, 0);
      acc[0][ct] = __builtin_amdgcn_mfma_f32_16x16x32_bf16(al0, bh, acc[0][ct], 0, 0, 0);
      acc[0][ct] = __builtin_amdgcn_mfma_f32_16x16x32_bf16(am0, bm, acc[0][ct], 0, 0, 0);
      acc[1][ct] = __builtin_amdgcn_mfma_f32_16x16x32_bf16(ah1, bh, acc[1][ct], 0, 0, 0);
      acc[1][ct] = __builtin_amdgcn_mfma_f32_16x16x32_bf16(ah1, bm, acc[1][ct], 0, 0, 0);
      acc[1][ct] = __builtin_amdgcn_mfma_f32_16x16x32_bf16(am1, bh, acc[1][ct], 0, 0, 0);
      acc[1][ct] = __builtin_amdgcn_mfma_f32_16x16x32_bf16(ah1, bl, acc[1][ct], 0, 0, 0);
      acc[1][ct] = __builtin_amdgcn_mfma_f32_16x16x32_bf16(al1, bh, acc[1][ct], 0, 0, 0);
      acc[1][ct] = __builtin_amdgcn_mfma_f32_16x16x32_bf16(am1, bm, acc[1][ct], 0, 0, 0);
    }
    __syncthreads();
  }

  // ---- epilogue: C/D layout col=lane&15 (+16*ct), row=rt*16+(lane>>4)*4+reg
  float local = 0.f;
#pragma unroll
  for (int rt = 0; rt < 2; ++rt) {
#pragma unroll
    for (int ct = 0; ct < 4; ++ct) {
      const int col = ct * 16 + (lane & 15);
      const float bc = bias ? bias[col] : 0.f;
#pragma unroll
      for (int reg = 0; reg < 4; ++reg) {
        const int grow = row0 + wave * 32 + rt * 16 + (lane >> 4) * 4 + reg;
        if (grow < M) {
          float y = acc[rt][ct][reg] + bc;
          if (relu) y = fmaxf(y, 0.f);
          if (pool) local += y * Wd[col];
          else C[(size_t)grow * 64 + col] = y;
        }
      }
    }
  }
  if (pool) {
    red[tid] = local;
    __syncthreads();
    for (int off = 128; off > 0; off >>= 1) {
      if (tid < off) red[tid] += red[tid + off];
      __syncthreads();
    }
    if (tid == 0) atomicAdd(accum, red[0]);
  }
}

__global__ void k_final(const float* __restrict__ accum, const float* __restrict__ b,
                        float* __restrict__ out) {
  out[0] = accum[0] + b[0];
}

// ------------------------- launch -------------------------------------------

extern "C" void kernel_launch(void* const* d_in, const int* in_sizes, int n_in,
                              void* d_out, int out_size, void* d_ws, size_t ws_size,
                              hipStream_t stream) {
  const float* h       = (const float*)d_in[0];
  const int*   src     = (const int*)d_in[1];
  const int*   dst     = (const int*)d_in[2];
  const int*   et      = (const int*)d_in[3];
  const float* W_fc    = (const float*)d_in[4];
  const float* W_rels  = (const float*)d_in[5];
  const float* W_loops = (const float*)d_in[6];
  const float* biases  = (const float*)d_in[7];
  const float* W_dense = (const float*)d_in[8];
  const float* b_dense = (const float*)d_in[9];
  float* out = (float*)d_out;

  const int N = in_sizes[0] / 128;
  const int E = in_sizes[1];

  size_t cur = 0;
  auto carve = [&](size_t bytes) -> char* {
    cur = (cur + 255) & ~(size_t)255;
    char* p = (char*)d_ws + cur;
    cur += bytes;
    return p;
  };
  int* deg        = (int*)carve((size_t)N * 4);
  int* scan       = (int*)carve((size_t)N * 4);
  int* part       = (int*)carve(1024 * 4);
  int* partx      = (int*)carve(1024 * 4);
  int* rowptr     = (int*)carve((size_t)(N + 1) * 4);
  int* cursor     = (int*)carve((size_t)N * 4);
  unsigned* edata = (unsigned*)carve((size_t)E * 4);
  float* xA       = (float*)carve((size_t)N * 64 * 4);
  float* xB       = (float*)carve((size_t)N * 64 * 4);
  float* pre      = (float*)carve((size_t)N * 256 * 4);
  float* accum    = (float*)carve(256);
  // fragment-ordered split B buffers
  unsigned short* Bfc[3];
  for (int p = 0; p < 3; ++p) Bfc[p] = (unsigned short*)carve((size_t)128 * 64 * 2);
  unsigned short* Blay[3][3];
  for (int l = 0; l < 3; ++l)
    for (int p = 0; p < 3; ++p) Blay[l][p] = (unsigned short*)carve((size_t)320 * 64 * 2);

  hipMemsetAsync(deg, 0, (size_t)N * 4, stream);
  hipMemsetAsync(accum, 0, 4, stream);

  // B pre-split (independent of everything else)
  k_bconv<<<(128 * 64 + 255) / 256, 256, 0, stream>>>(W_fc, 128, nullptr, 0,
                                                      Bfc[0], Bfc[1], Bfc[2]);
  for (int l = 0; l < 3; ++l)
    k_bconv<<<(320 * 64 + 255) / 256, 256, 0, stream>>>(
        W_rels + (size_t)l * 4 * 64 * 64, 256, W_loops + (size_t)l * 64 * 64, 64,
        Blay[l][0], Blay[l][1], Blay[l][2]);

  // CSR build
  const int eb = (E + 255) / 256;
  k_degree<<<eb, 256, 0, stream>>>(dst, deg, E);
  const int nblk = (N + 1023) / 1024;
  k_scan1<<<nblk, 1024, 0, stream>>>(deg, scan, part, N);
  k_scan2<<<1, 1024, 0, stream>>>(part, partx, nblk);
  k_scan3<<<(N + 255) / 256, 256, 0, stream>>>(scan, deg, partx, rowptr, cursor, N, E);
  k_scatter<<<eb, 256, 0, stream>>>(src, dst, et, cursor, edata, E);

  const int gb = (N + 127) / 128;
  // x = h @ W_fc
  k_mgemm<<<gb, 256, 0, stream>>>(h, 128, nullptr, 0,
                                  Bfc[0], Bfc[1], Bfc[2],
                                  nullptr, 0, xA, N, nullptr, nullptr, 0);

  float* xin = xA;
  float* xout = xB;
  for (int l = 0; l < 3; ++l) {
    k_agg<<<(N + 3) / 4, 256, 0, stream>>>(rowptr, edata, xin, pre, N);
    const int last = (l == 2);
    k_mgemm<<<gb, 256, 0, stream>>>(pre, 256, xin, 64,
                                    Blay[l][0], Blay[l][1], Blay[l][2],
                                    biases + (size_t)l * 64, 1,
                                    last ? nullptr : xout, N,
                                    last ? W_dense : nullptr, accum, last);
    float* t = xin; xin = xout; xout = t;
  }

  k_final<<<1, 1, 0, stream>>>(accum, b_dense, out);
}